// Round 1
// baseline (4135.932 us; speedup 1.0000x reference)
//
#include <hip/hip_runtime.h>
#include <cstdint>
#include <cstddef>

#define NEG_SLOPE 0.2f

// order-preserving float -> uint encoding (monotone), init value 0 < enc(-inf)
__device__ __forceinline__ unsigned fenc(float f) {
  unsigned b = __float_as_uint(f);
  return b ^ ((unsigned)((int)b >> 31) | 0x80000000u);
}
__device__ __forceinline__ float fdec(unsigned u) {
  unsigned b = (u & 0x80000000u) ? (u ^ 0x80000000u) : ~u;
  return __uint_as_float(b);
}

// ---------------- fp32 tiled GEMM: C[MxN] = A[MxK] @ B[KxN], row-major ------
template<int BM, int BN, int BK>
__global__ __launch_bounds__(256) void gemm_f32(const float* __restrict__ A,
                                                const float* __restrict__ B,
                                                float* __restrict__ C,
                                                int M, int N, int K) {
  __shared__ float As[BK][BM + 4];
  __shared__ float Bs[BK][BN + 4];
  const int tid = threadIdx.x;
  const int brow = blockIdx.y * BM;
  const int bcol = blockIdx.x * BN;
  const int tx = tid & 15;   // 16 cols of threads
  const int ty = tid >> 4;   // 16 rows of threads
  float acc[4][4] = {};
  for (int k0 = 0; k0 < K; k0 += BK) {
    #pragma unroll
    for (int i = tid; i < BM * BK; i += 256) {
      int r = i / BK, c = i % BK;
      int gr = brow + r;
      As[c][r] = (gr < M) ? A[(size_t)gr * K + k0 + c] : 0.f;
    }
    #pragma unroll
    for (int i = tid; i < BK * BN; i += 256) {
      int r = i / BN, c = i % BN;
      Bs[r][c] = B[(size_t)(k0 + r) * N + bcol + c];
    }
    __syncthreads();
    #pragma unroll
    for (int k = 0; k < BK; ++k) {
      float4 a = *(const float4*)&As[k][ty * 4];
      float4 b = *(const float4*)&Bs[k][tx * 4];
      float av[4] = {a.x, a.y, a.z, a.w};
      float bv[4] = {b.x, b.y, b.z, b.w};
      #pragma unroll
      for (int i = 0; i < 4; ++i)
        #pragma unroll
        for (int j = 0; j < 4; ++j)
          acc[i][j] = fmaf(av[i], bv[j], acc[i][j]);
    }
    __syncthreads();
  }
  #pragma unroll
  for (int i = 0; i < 4; ++i) {
    int gr = brow + ty * 4 + i;
    if (gr < M) {
      float4 v = {acc[i][0], acc[i][1], acc[i][2], acc[i][3]};
      *(float4*)&C[(size_t)gr * N + bcol + tx * 4] = v;
    }
  }
}

// ---------------- per-node attention coefficients ----------------------------
// layer1: H=4, C=64 (F=256). wave per node; lane holds 4 ch; reduce within 16 lanes.
__global__ __launch_bounds__(256) void attn_coef_h4(const float* __restrict__ xl,
                                                    const float* __restrict__ att_src,
                                                    const float* __restrict__ att_dst,
                                                    float* __restrict__ a_src,
                                                    float* __restrict__ a_dst, int n) {
  int wid = (blockIdx.x * 256 + threadIdx.x) >> 6;
  int lane = threadIdx.x & 63;
  if (wid >= n) return;
  float4 v  = *(const float4*)(xl + (size_t)wid * 256 + lane * 4);
  float4 as = *(const float4*)(att_src + lane * 4);
  float4 ad = *(const float4*)(att_dst + lane * 4);
  float s = v.x * as.x + v.y * as.y + v.z * as.z + v.w * as.w;
  float d = v.x * ad.x + v.y * ad.y + v.z * ad.z + v.w * ad.w;
  #pragma unroll
  for (int off = 1; off < 16; off <<= 1) {
    s += __shfl_xor(s, off);
    d += __shfl_xor(d, off);
  }
  if ((lane & 15) == 0) {
    int h = lane >> 4;
    a_src[(size_t)wid * 4 + h] = s;
    a_dst[(size_t)wid * 4 + h] = d;
  }
}

// layer2: H=1, C=128. wave per node; lane holds 2 ch; full-wave reduce.
__global__ __launch_bounds__(256) void attn_coef_h1(const float* __restrict__ xl,
                                                    const float* __restrict__ att_src,
                                                    const float* __restrict__ att_dst,
                                                    float* __restrict__ a_src,
                                                    float* __restrict__ a_dst, int n) {
  int wid = (blockIdx.x * 256 + threadIdx.x) >> 6;
  int lane = threadIdx.x & 63;
  if (wid >= n) return;
  float2 v  = *(const float2*)(xl + (size_t)wid * 128 + lane * 2);
  float2 as = *(const float2*)(att_src + lane * 2);
  float2 ad = *(const float2*)(att_dst + lane * 2);
  float s = v.x * as.x + v.y * as.y;
  float d = v.x * ad.x + v.y * ad.y;
  #pragma unroll
  for (int off = 1; off < 64; off <<= 1) {
    s += __shfl_xor(s, off);
    d += __shfl_xor(d, off);
  }
  if (lane == 0) { a_src[wid] = s; a_dst[wid] = d; }
}

// ---------------- edge softmax passes (thread per edge) ----------------------
template<int H>
__global__ __launch_bounds__(256) void edge_max_k(const int* __restrict__ esrc,
                                                  const int* __restrict__ edst,
                                                  const float* __restrict__ a_src,
                                                  const float* __restrict__ a_dst,
                                                  unsigned* __restrict__ m, int E, int N) {
  int e = blockIdx.x * 256 + threadIdx.x;
  if (e >= E + N) return;
  int s = (e < E) ? esrc[e] : (e - E);
  int d = (e < E) ? edst[e] : (e - E);
  #pragma unroll
  for (int h = 0; h < H; ++h) {
    float v = a_src[(size_t)s * H + h] + a_dst[(size_t)d * H + h];
    v = (v > 0.f) ? v : NEG_SLOPE * v;
    atomicMax(m + (size_t)d * H + h, fenc(v));
  }
}

template<int H>
__global__ __launch_bounds__(256) void edge_den_k(const int* __restrict__ esrc,
                                                  const int* __restrict__ edst,
                                                  const float* __restrict__ a_src,
                                                  const float* __restrict__ a_dst,
                                                  const unsigned* __restrict__ m,
                                                  float* __restrict__ den, int E, int N) {
  int e = blockIdx.x * 256 + threadIdx.x;
  if (e >= E + N) return;
  int s = (e < E) ? esrc[e] : (e - E);
  int d = (e < E) ? edst[e] : (e - E);
  #pragma unroll
  for (int h = 0; h < H; ++h) {
    float v = a_src[(size_t)s * H + h] + a_dst[(size_t)d * H + h];
    v = (v > 0.f) ? v : NEG_SLOPE * v;
    float p = expf(v - fdec(m[(size_t)d * H + h]));
    unsafeAtomicAdd(den + (size_t)d * H + h, p);
  }
}

// ---------------- aggregation: wave per edge, float4 per lane ----------------
template<int H, int C>
__global__ __launch_bounds__(256) void edge_agg(const int* __restrict__ esrc,
                                                const int* __restrict__ edst,
                                                const float* __restrict__ a_src,
                                                const float* __restrict__ a_dst,
                                                const unsigned* __restrict__ m,
                                                const float* __restrict__ den,
                                                const float* __restrict__ xl,
                                                float* __restrict__ out, int E, int N) {
  constexpr int F = H * C;
  constexpr int PER = F / 64;
  int wid = (blockIdx.x * 256 + threadIdx.x) >> 6;
  int lane = threadIdx.x & 63;
  if (wid >= E + N) return;
  int s = (wid < E) ? esrc[wid] : (wid - E);
  int d = (wid < E) ? edst[wid] : (wid - E);
  int c0 = lane * PER;
  int h = c0 / C;
  float v = a_src[(size_t)s * H + h] + a_dst[(size_t)d * H + h];
  v = (v > 0.f) ? v : NEG_SLOPE * v;
  float alpha = expf(v - fdec(m[(size_t)d * H + h])) / (den[(size_t)d * H + h] + 1e-16f);
  const float* xs = xl + (size_t)s * F + c0;
  float* od = out + (size_t)d * F + c0;
  if (PER == 4) {
    float4 xv = *(const float4*)xs;
    unsafeAtomicAdd(od + 0, xv.x * alpha);
    unsafeAtomicAdd(od + 1, xv.y * alpha);
    unsafeAtomicAdd(od + 2, xv.z * alpha);
    unsafeAtomicAdd(od + 3, xv.w * alpha);
  } else {
    float2 xv = *(const float2*)xs;
    unsafeAtomicAdd(od + 0, xv.x * alpha);
    unsafeAtomicAdd(od + 1, xv.y * alpha);
  }
}

// ---------------- elementwise bias + relu (float4) ---------------------------
__global__ __launch_bounds__(256) void bias_relu_k(float* __restrict__ h,
                                                   const float* __restrict__ bias,
                                                   size_t total4, int F4) {
  size_t i = (size_t)blockIdx.x * 256 + threadIdx.x;
  if (i >= total4) return;
  float4 v = ((float4*)h)[i];
  float4 b = ((const float4*)bias)[i % F4];
  v.x = fmaxf(v.x + b.x, 0.f);
  v.y = fmaxf(v.y + b.y, 0.f);
  v.z = fmaxf(v.z + b.z, 0.f);
  v.w = fmaxf(v.w + b.w, 0.f);
  ((float4*)h)[i] = v;
}

// ---------------- global mean pool (batch sorted) -----------------------------
// block: 256 threads over 128 ch x 2 node-phases; 256 nodes per block.
// run-length accumulate in registers (batch sorted => few flushes).
__global__ __launch_bounds__(256) void pool_k(const float* __restrict__ h,
                                              const int* __restrict__ batch,
                                              float* __restrict__ pool, int n) {
  int ch = threadIdx.x & 127;
  int half = threadIdx.x >> 7;
  int n0 = blockIdx.x * 256;
  float run = 0.f;
  int curg = -1;
  for (int r = half; r < 256; r += 2) {
    int node = n0 + r;
    if (node >= n) break;
    int g = batch[node];
    if (g != curg) {
      if (curg >= 0) unsafeAtomicAdd(pool + curg * 128 + ch, run);
      run = 0.f;
      curg = g;
    }
    run += h[(size_t)node * 128 + ch];
  }
  if (curg >= 0) unsafeAtomicAdd(pool + curg * 128 + ch, run);
}

__global__ __launch_bounds__(256) void finalize_k(const float* __restrict__ pool,
                                                  const int* __restrict__ batch,
                                                  const float* __restrict__ bias2,
                                                  float* __restrict__ out, int n) {
  int t = blockIdx.x * 256 + threadIdx.x;
  if (t >= 8 * 128) return;
  int g = t >> 7, c = t & 127;
  // counts via binary search on sorted batch
  int a = 0, b = n;
  while (a < b) { int mid = (a + b) >> 1; if (batch[mid] < g) a = mid + 1; else b = mid; }
  int lo = a;
  b = n;
  while (a < b) { int mid = (a + b) >> 1; if (batch[mid] < g + 1) a = mid + 1; else b = mid; }
  int hi = a;
  float cnt = (float)(hi - lo);
  out[t] = pool[t] / fmaxf(cnt, 1.f) + bias2[c];
}

extern "C" void kernel_launch(void* const* d_in, const int* in_sizes, int n_in,
                              void* d_out, int out_size, void* d_ws, size_t ws_size,
                              hipStream_t stream) {
  const float* x        = (const float*)d_in[0];
  const int*   ei       = (const int*)d_in[1];
  const int*   batch    = (const int*)d_in[2];
  const float* W1       = (const float*)d_in[3];
  const float* att_src1 = (const float*)d_in[4];
  const float* att_dst1 = (const float*)d_in[5];
  const float* bias1    = (const float*)d_in[6];
  const float* W2       = (const float*)d_in[7];
  const float* att_src2 = (const float*)d_in[8];
  const float* att_dst2 = (const float*)d_in[9];
  const float* bias2    = (const float*)d_in[10];
  float* out = (float*)d_out;

  const int E  = in_sizes[1] / 2;
  const int NN = in_sizes[2];     // nodes
  const int ET = E + NN;
  const int* esrc = ei;
  const int* edst = ei + E;

  // ---- workspace layout (≈106.5 MB) ----
  char* w = (char*)d_ws;
  const size_t SZ_XL1 = (size_t)NN * 256 * 4;  // 51.2 MB
  float*    bufA   = (float*)w;                       // xl1; later xl2 (first half) + out2 (second half)
  float*    bufB   = (float*)(w + SZ_XL1);            // out1 / h1
  char*     p      = w + 2 * SZ_XL1;
  float*    a_src1 = (float*)p; p += (size_t)NN * 4 * 4;
  float*    a_dst1 = (float*)p; p += (size_t)NN * 4 * 4;
  unsigned* m1     = (unsigned*)p; p += (size_t)NN * 4 * 4;
  float*    den1   = (float*)p; p += (size_t)NN * 4 * 4;
  float*    a_src2 = (float*)p; p += (size_t)NN * 4;
  float*    a_dst2 = (float*)p; p += (size_t)NN * 4;
  unsigned* m2     = (unsigned*)p; p += (size_t)NN * 4;
  float*    den2   = (float*)p; p += (size_t)NN * 4;
  float*    pool   = (float*)p; p += 8 * 128 * 4;
  float*    xl2    = bufA;
  float*    out2   = (float*)(w + SZ_XL1 / 2);        // bufA second half

  dim3 blk(256);

  // ---- init (atomics accumulate, so every call re-zeroes) ----
  hipMemsetAsync(bufB, 0, SZ_XL1, stream);
  hipMemsetAsync(m1,   0, (size_t)NN * 4 * 4, stream);
  hipMemsetAsync(den1, 0, (size_t)NN * 4 * 4, stream);
  hipMemsetAsync(m2,   0, (size_t)NN * 4, stream);
  hipMemsetAsync(den2, 0, (size_t)NN * 4, stream);
  hipMemsetAsync(pool, 0, 8 * 128 * 4, stream);

  // ---- layer 1 ----
  {
    dim3 grid(256 / 64, (NN + 63) / 64);
    gemm_f32<64, 64, 16><<<grid, blk, 0, stream>>>(x, W1, bufA, NN, 256, 128);
  }
  attn_coef_h4<<<(NN + 3) / 4, blk, 0, stream>>>(bufA, att_src1, att_dst1, a_src1, a_dst1, NN);
  {
    int nb = (ET + 255) / 256;
    edge_max_k<4><<<nb, blk, 0, stream>>>(esrc, edst, a_src1, a_dst1, m1, E, NN);
    edge_den_k<4><<<nb, blk, 0, stream>>>(esrc, edst, a_src1, a_dst1, m1, den1, E, NN);
  }
  edge_agg<4, 64><<<(ET + 3) / 4, blk, 0, stream>>>(esrc, edst, a_src1, a_dst1, m1, den1,
                                                    bufA, bufB, E, NN);
  bias_relu_k<<<((size_t)NN * 64 + 255) / 256, blk, 0, stream>>>(bufB, bias1, (size_t)NN * 64, 64);

  // xl1 now dead -> safe to zero out2 region (second half of bufA)
  hipMemsetAsync(out2, 0, SZ_XL1 / 2, stream);

  // ---- layer 2 ----
  {
    dim3 grid(128 / 64, (NN + 63) / 64);
    gemm_f32<64, 64, 16><<<grid, blk, 0, stream>>>(bufB, W2, xl2, NN, 128, 256);
  }
  attn_coef_h1<<<(NN + 3) / 4, blk, 0, stream>>>(xl2, att_src2, att_dst2, a_src2, a_dst2, NN);
  {
    int nb = (ET + 255) / 256;
    edge_max_k<1><<<nb, blk, 0, stream>>>(esrc, edst, a_src2, a_dst2, m2, E, NN);
    edge_den_k<1><<<nb, blk, 0, stream>>>(esrc, edst, a_src2, a_dst2, m2, den2, E, NN);
  }
  edge_agg<1, 128><<<(ET + 3) / 4, blk, 0, stream>>>(esrc, edst, a_src2, a_dst2, m2, den2,
                                                     xl2, out2, E, NN);

  // ---- pool + finalize ----
  pool_k<<<(NN + 255) / 256, blk, 0, stream>>>(out2, batch, pool, NN);
  finalize_k<<<4, blk, 0, stream>>>(pool, batch, bias2, out, NN);
}

// Round 2
// 680.340 us; speedup vs baseline: 6.0792x; 6.0792x over previous
//
#include <hip/hip_runtime.h>
#include <cstdint>
#include <cstddef>

#define NEG_SLOPE 0.2f

// ---------------- fp32 tiled GEMM: C[MxN] = A[MxK] @ B[KxN], row-major ------
template<int BM, int BN, int BK>
__global__ __launch_bounds__(256) void gemm_f32(const float* __restrict__ A,
                                                const float* __restrict__ B,
                                                float* __restrict__ C,
                                                int M, int N, int K) {
  __shared__ float As[BK][BM + 4];
  __shared__ float Bs[BK][BN + 4];
  const int tid = threadIdx.x;
  const int brow = blockIdx.y * BM;
  const int bcol = blockIdx.x * BN;
  const int tx = tid & 15;
  const int ty = tid >> 4;
  float acc[4][4] = {};
  for (int k0 = 0; k0 < K; k0 += BK) {
    #pragma unroll
    for (int i = tid; i < BM * BK; i += 256) {
      int r = i / BK, c = i % BK;
      int gr = brow + r;
      As[c][r] = (gr < M) ? A[(size_t)gr * K + k0 + c] : 0.f;
    }
    #pragma unroll
    for (int i = tid; i < BK * BN; i += 256) {
      int r = i / BN, c = i % BN;
      Bs[r][c] = B[(size_t)(k0 + r) * N + bcol + c];
    }
    __syncthreads();
    #pragma unroll
    for (int k = 0; k < BK; ++k) {
      float4 a = *(const float4*)&As[k][ty * 4];
      float4 b = *(const float4*)&Bs[k][tx * 4];
      float av[4] = {a.x, a.y, a.z, a.w};
      float bv[4] = {b.x, b.y, b.z, b.w};
      #pragma unroll
      for (int i = 0; i < 4; ++i)
        #pragma unroll
        for (int j = 0; j < 4; ++j)
          acc[i][j] = fmaf(av[i], bv[j], acc[i][j]);
    }
    __syncthreads();
  }
  #pragma unroll
  for (int i = 0; i < 4; ++i) {
    int gr = brow + ty * 4 + i;
    if (gr < M) {
      float4 v = {acc[i][0], acc[i][1], acc[i][2], acc[i][3]};
      *(float4*)&C[(size_t)gr * N + bcol + tx * 4] = v;
    }
  }
}

// ---------------- per-node attention coefficients ----------------------------
__global__ __launch_bounds__(256) void attn_coef_h4(const float* __restrict__ xl,
                                                    const float* __restrict__ att_src,
                                                    const float* __restrict__ att_dst,
                                                    float* __restrict__ a_src,
                                                    float* __restrict__ a_dst, int n) {
  int wid = (blockIdx.x * 256 + threadIdx.x) >> 6;
  int lane = threadIdx.x & 63;
  if (wid >= n) return;
  float4 v  = *(const float4*)(xl + (size_t)wid * 256 + lane * 4);
  float4 as = *(const float4*)(att_src + lane * 4);
  float4 ad = *(const float4*)(att_dst + lane * 4);
  float s = v.x * as.x + v.y * as.y + v.z * as.z + v.w * as.w;
  float d = v.x * ad.x + v.y * ad.y + v.z * ad.z + v.w * ad.w;
  #pragma unroll
  for (int off = 1; off < 16; off <<= 1) {
    s += __shfl_xor(s, off);
    d += __shfl_xor(d, off);
  }
  if ((lane & 15) == 0) {
    int h = lane >> 4;
    a_src[(size_t)wid * 4 + h] = s;
    a_dst[(size_t)wid * 4 + h] = d;
  }
}

__global__ __launch_bounds__(256) void attn_coef_h1(const float* __restrict__ xl,
                                                    const float* __restrict__ att_src,
                                                    const float* __restrict__ att_dst,
                                                    float* __restrict__ a_src,
                                                    float* __restrict__ a_dst, int n) {
  int wid = (blockIdx.x * 256 + threadIdx.x) >> 6;
  int lane = threadIdx.x & 63;
  if (wid >= n) return;
  float2 v  = *(const float2*)(xl + (size_t)wid * 128 + lane * 2);
  float2 as = *(const float2*)(att_src + lane * 2);
  float2 ad = *(const float2*)(att_dst + lane * 2);
  float s = v.x * as.x + v.y * as.y;
  float d = v.x * ad.x + v.y * ad.y;
  #pragma unroll
  for (int off = 1; off < 64; off <<= 1) {
    s += __shfl_xor(s, off);
    d += __shfl_xor(d, off);
  }
  if (lane == 0) { a_src[wid] = s; a_dst[wid] = d; }
}

// ---------------- CSR build: histogram -> scan -> scatter --------------------
__global__ __launch_bounds__(256) void hist_k(const int* __restrict__ edst,
                                              int* __restrict__ hist, int E, int N) {
  int e = blockIdx.x * 256 + threadIdx.x;
  if (e >= E + N) return;
  int d = (e < E) ? edst[e] : (e - E);
  atomicAdd(hist + d, 1);
}

__global__ __launch_bounds__(1024) void scan_k(const int* __restrict__ hist,
                                               int* __restrict__ rowptr,
                                               int* __restrict__ cursor, int n) {
  __shared__ int tmp[1024];
  int carry = 0;
  for (int base = 0; base < n; base += 1024) {
    int i = base + threadIdx.x;
    int v = (i < n) ? hist[i] : 0;
    tmp[threadIdx.x] = v;
    __syncthreads();
    #pragma unroll
    for (int off = 1; off < 1024; off <<= 1) {
      int t = (threadIdx.x >= (unsigned)off) ? tmp[threadIdx.x - off] : 0;
      __syncthreads();
      tmp[threadIdx.x] += t;
      __syncthreads();
    }
    if (i < n) {
      int excl = carry + tmp[threadIdx.x] - v;
      rowptr[i] = excl;
      cursor[i] = excl;
    }
    carry += tmp[1023];
    __syncthreads();
  }
  if (threadIdx.x == 0) rowptr[n] = carry;
}

__global__ __launch_bounds__(256) void scatter_k(const int* __restrict__ esrc,
                                                 const int* __restrict__ edst,
                                                 int* __restrict__ cursor,
                                                 int* __restrict__ csr_src, int E, int N) {
  int e = blockIdx.x * 256 + threadIdx.x;
  if (e >= E + N) return;
  int s = (e < E) ? esrc[e] : (e - E);
  int d = (e < E) ? edst[e] : (e - E);
  int pos = atomicAdd(cursor + d, 1);
  csr_src[pos] = s;
}

// ---------------- fused segment softmax + aggregation (wave per node) --------
// H*C = F; lane owns PER = F/64 channels; head h = (lane*PER)/C.
template<int H, int C, bool RELU>
__global__ __launch_bounds__(256) void agg_csr(const int* __restrict__ rowptr,
                                               const int* __restrict__ csr_src,
                                               const float* __restrict__ a_src,
                                               const float* __restrict__ a_dst,
                                               const float* __restrict__ xl,
                                               const float* __restrict__ bias,
                                               float* __restrict__ out, int n) {
  constexpr int F = H * C;
  constexpr int PER = F / 64;
  int wid = (blockIdx.x * 256 + threadIdx.x) >> 6;
  int lane = threadIdx.x & 63;
  if (wid >= n) return;
  const int h = (lane * PER) / C;
  const int beg = rowptr[wid];
  const int end = rowptr[wid + 1];
  const float adh = a_dst[(size_t)wid * H + h];

  // pass 1: segment max (every node has its self-loop, so end > beg)
  float m = -1e30f;
  for (int j = beg; j < end; ++j) {
    int s = csr_src[j];
    float v = a_src[(size_t)s * H + h] + adh;
    v = (v > 0.f) ? v : NEG_SLOPE * v;
    m = fmaxf(m, v);
  }

  // pass 2: denominator + weighted gather-accumulate
  float den = 0.f;
  float acc[PER] = {};
  for (int j = beg; j < end; ++j) {
    int s = csr_src[j];
    float v = a_src[(size_t)s * H + h] + adh;
    v = (v > 0.f) ? v : NEG_SLOPE * v;
    float p = __expf(v - m);
    den += p;
    const float* xs = xl + (size_t)s * F + lane * PER;
    if constexpr (PER == 4) {
      float4 xv = *(const float4*)xs;
      acc[0] = fmaf(p, xv.x, acc[0]);
      acc[1] = fmaf(p, xv.y, acc[1]);
      acc[2] = fmaf(p, xv.z, acc[2]);
      acc[3] = fmaf(p, xv.w, acc[3]);
    } else {
      float2 xv = *(const float2*)xs;
      acc[0] = fmaf(p, xv.x, acc[0]);
      acc[1] = fmaf(p, xv.y, acc[1]);
    }
  }

  float inv = 1.f / (den + 1e-16f);
  float* od = out + (size_t)wid * F + lane * PER;
  if constexpr (PER == 4) {
    float4 o;
    o.x = acc[0] * inv; o.y = acc[1] * inv; o.z = acc[2] * inv; o.w = acc[3] * inv;
    if constexpr (RELU) {
      float4 b = *(const float4*)(bias + lane * 4);
      o.x = fmaxf(o.x + b.x, 0.f); o.y = fmaxf(o.y + b.y, 0.f);
      o.z = fmaxf(o.z + b.z, 0.f); o.w = fmaxf(o.w + b.w, 0.f);
    }
    *(float4*)od = o;
  } else {
    float2 o;
    o.x = acc[0] * inv; o.y = acc[1] * inv;
    if constexpr (RELU) {
      float2 b = *(const float2*)(bias + lane * 2);
      o.x = fmaxf(o.x + b.x, 0.f); o.y = fmaxf(o.y + b.y, 0.f);
    }
    *(float2*)od = o;
  }
}

// ---------------- global mean pool (batch sorted) ----------------------------
__global__ __launch_bounds__(256) void pool_k(const float* __restrict__ h,
                                              const int* __restrict__ batch,
                                              float* __restrict__ pool, int n) {
  int ch = threadIdx.x & 127;
  int half = threadIdx.x >> 7;
  int n0 = blockIdx.x * 256;
  float run = 0.f;
  int curg = -1;
  for (int r = half; r < 256; r += 2) {
    int node = n0 + r;
    if (node >= n) break;
    int g = batch[node];
    if (g != curg) {
      if (curg >= 0) unsafeAtomicAdd(pool + curg * 128 + ch, run);
      run = 0.f;
      curg = g;
    }
    run += h[(size_t)node * 128 + ch];
  }
  if (curg >= 0) unsafeAtomicAdd(pool + curg * 128 + ch, run);
}

__global__ __launch_bounds__(256) void finalize_k(const float* __restrict__ pool,
                                                  const int* __restrict__ batch,
                                                  const float* __restrict__ bias2,
                                                  float* __restrict__ out, int n) {
  int t = blockIdx.x * 256 + threadIdx.x;
  if (t >= 8 * 128) return;
  int g = t >> 7, c = t & 127;
  int a = 0, b = n;
  while (a < b) { int mid = (a + b) >> 1; if (batch[mid] < g) a = mid + 1; else b = mid; }
  int lo = a;
  b = n;
  while (a < b) { int mid = (a + b) >> 1; if (batch[mid] < g + 1) a = mid + 1; else b = mid; }
  int hi = a;
  float cnt = (float)(hi - lo);
  out[t] = pool[t] / fmaxf(cnt, 1.f) + bias2[c];
}

extern "C" void kernel_launch(void* const* d_in, const int* in_sizes, int n_in,
                              void* d_out, int out_size, void* d_ws, size_t ws_size,
                              hipStream_t stream) {
  const float* x        = (const float*)d_in[0];
  const int*   ei       = (const int*)d_in[1];
  const int*   batch    = (const int*)d_in[2];
  const float* W1       = (const float*)d_in[3];
  const float* att_src1 = (const float*)d_in[4];
  const float* att_dst1 = (const float*)d_in[5];
  const float* bias1    = (const float*)d_in[6];
  const float* W2       = (const float*)d_in[7];
  const float* att_src2 = (const float*)d_in[8];
  const float* att_dst2 = (const float*)d_in[9];
  const float* bias2    = (const float*)d_in[10];
  float* out = (float*)d_out;

  const int E  = in_sizes[1] / 2;
  const int NN = in_sizes[2];
  const int ET = E + NN;
  const int* esrc = ei;
  const int* edst = ei + E;

  // ---- workspace layout (~108.5 MB) ----
  char* w = (char*)d_ws;
  const size_t SZ_XL1 = (size_t)NN * 256 * 4;       // 51.2 MB
  float* bufA   = (float*)w;                        // xl1; later xl2 | out2
  float* bufB   = (float*)(w + SZ_XL1);             // out1 / h1
  char*  p      = w + 2 * SZ_XL1;
  float* a_src1 = (float*)p; p += (size_t)NN * 4 * 4;
  float* a_dst1 = (float*)p; p += (size_t)NN * 4 * 4;
  float* a_src2 = (float*)p; p += (size_t)NN * 4;
  float* a_dst2 = (float*)p; p += (size_t)NN * 4;
  int*   rowptr = (int*)p;   p += (size_t)(NN + 1) * 4;
  int*   cursor = (int*)p;   p += (size_t)NN * 4;
  int*   hist   = (int*)p;   p += (size_t)NN * 4;
  int*   csrsrc = (int*)p;   p += (size_t)ET * 4;
  float* pool   = (float*)p; p += 8 * 128 * 4;
  float* xl2    = bufA;                              // NN*128 floats
  float* out2   = (float*)(w + SZ_XL1 / 2);          // NN*128 floats

  dim3 blk(256);
  int nbE = (ET + 255) / 256;
  int nbN4 = (NN + 3) / 4;

  // ---- CSR build (no dependence on features; do it first) ----
  hipMemsetAsync(hist, 0, (size_t)NN * 4, stream);
  hipMemsetAsync(pool, 0, 8 * 128 * 4, stream);
  hist_k<<<nbE, blk, 0, stream>>>(edst, hist, E, NN);
  scan_k<<<1, 1024, 0, stream>>>(hist, rowptr, cursor, NN);
  scatter_k<<<nbE, blk, 0, stream>>>(esrc, edst, cursor, csrsrc, E, NN);

  // ---- layer 1 ----
  {
    dim3 grid(256 / 64, (NN + 63) / 64);
    gemm_f32<64, 64, 16><<<grid, blk, 0, stream>>>(x, W1, bufA, NN, 256, 128);
  }
  attn_coef_h4<<<nbN4, blk, 0, stream>>>(bufA, att_src1, att_dst1, a_src1, a_dst1, NN);
  agg_csr<4, 64, true><<<nbN4, blk, 0, stream>>>(rowptr, csrsrc, a_src1, a_dst1,
                                                 bufA, bias1, bufB, NN);

  // ---- layer 2 ----
  {
    dim3 grid(128 / 64, (NN + 63) / 64);
    gemm_f32<64, 64, 16><<<grid, blk, 0, stream>>>(bufB, W2, xl2, NN, 128, 256);
  }
  attn_coef_h1<<<nbN4, blk, 0, stream>>>(xl2, att_src2, att_dst2, a_src2, a_dst2, NN);
  agg_csr<1, 128, false><<<nbN4, blk, 0, stream>>>(rowptr, csrsrc, a_src2, a_dst2,
                                                   xl2, nullptr, out2, NN);

  // ---- pool + finalize ----
  pool_k<<<(NN + 255) / 256, blk, 0, stream>>>(out2, batch, pool, NN);
  finalize_k<<<4, blk, 0, stream>>>(pool, batch, bias2, out, NN);
}

// Round 3
// 506.571 us; speedup vs baseline: 8.1646x; 1.3430x over previous
//
#include <hip/hip_runtime.h>
#include <cstdint>
#include <cstddef>

#define NEG_SLOPE 0.2f

typedef __attribute__((ext_vector_type(8))) short bf16x8;
typedef __attribute__((ext_vector_type(4))) float f32x4;

__device__ __forceinline__ ushort f2b(float f) {   // fp32 -> bf16 RNE
  unsigned u = __float_as_uint(f);
  return (ushort)((u + 0x7FFFu + ((u >> 16) & 1)) >> 16);
}
__device__ __forceinline__ float b2f(ushort b) {
  return __uint_as_float(((unsigned)b) << 16);
}

// ---------------- fp32 -> bf16 conversion ------------------------------------
__global__ __launch_bounds__(256) void conv_bf16(const float* __restrict__ in,
                                                 ushort* __restrict__ out, size_t total) {
  size_t i = ((size_t)blockIdx.x * 256 + threadIdx.x) * 4;
  if (i + 3 < total) {
    float4 v = *(const float4*)(in + i);
    ushort4 o = {f2b(v.x), f2b(v.y), f2b(v.z), f2b(v.w)};
    *(ushort4*)(out + i) = o;
  } else {
    for (; i < total; ++i) out[i] = f2b(in[i]);
  }
}

// ---------------- pack W[K][N] fp32 -> bf16 [K/8][N][8] ----------------------
__global__ __launch_bounds__(256) void pack_w(const float* __restrict__ W,
                                              ushort* __restrict__ Bp, int K, int N) {
  int i = blockIdx.x * 256 + threadIdx.x;
  if (i >= K * N) return;
  int k = i / N, n = i % N;
  Bp[((size_t)(k >> 3) * N + n) * 8 + (k & 7)] = f2b(W[i]);
}

// ---------------- bf16 MFMA GEMM: C[MxN] = A[MxK] @ B[KxN] -------------------
// A row-major bf16; Bp packed [K/8][N][8] bf16; C row-major bf16.
// wave per 16-row strip; frag layout: A lane: row=lane&15, k=(lane>>4)*8+j;
// B lane: col=lane&15, k=(lane>>4)*8+j; C/D lane: col=lane&15, row=(lane>>4)*4+i.
template<int N, int K>
__global__ __launch_bounds__(256) void gemm_mfma(const ushort* __restrict__ A,
                                                 const ushort* __restrict__ Bp,
                                                 ushort* __restrict__ C, int M) {
  const int wave = threadIdx.x >> 6;
  const int lane = threadIdx.x & 63;
  const int strips = M / 16;                  // M divisible by 16 here (50000)
  const int strip = blockIdx.x * 4 + wave;
  if (strip >= strips) return;
  const int r = lane & 15, kg = lane >> 4;
  const int row = strip * 16 + r;

  bf16x8 a[K / 32];
  #pragma unroll
  for (int k0 = 0; k0 < K / 32; ++k0)
    a[k0] = *(const bf16x8*)(A + (size_t)row * K + k0 * 32 + kg * 8);

  #pragma unroll 2
  for (int n0 = 0; n0 < N / 16; ++n0) {
    f32x4 acc = {0.f, 0.f, 0.f, 0.f};
    #pragma unroll
    for (int k0 = 0; k0 < K / 32; ++k0) {
      bf16x8 b = *(const bf16x8*)(Bp + ((size_t)(k0 * 4 + kg) * N + n0 * 16 + r) * 8);
      acc = __builtin_amdgcn_mfma_f32_16x16x32_bf16(a[k0], b, acc, 0, 0, 0);
    }
    #pragma unroll
    for (int i = 0; i < 4; ++i)
      C[((size_t)strip * 16 + kg * 4 + i) * N + n0 * 16 + r] = f2b(acc[i]);
  }
}

// ---------------- per-node attention coefficients (bf16 xl) ------------------
__global__ __launch_bounds__(256) void attn_coef_h4(const ushort* __restrict__ xl,
                                                    const float* __restrict__ att_src,
                                                    const float* __restrict__ att_dst,
                                                    float* __restrict__ a_src,
                                                    float* __restrict__ a_dst, int n) {
  int wid = (blockIdx.x * 256 + threadIdx.x) >> 6;
  int lane = threadIdx.x & 63;
  if (wid >= n) return;
  ushort4 vb = *(const ushort4*)(xl + (size_t)wid * 256 + lane * 4);
  float4 as = *(const float4*)(att_src + lane * 4);
  float4 ad = *(const float4*)(att_dst + lane * 4);
  float v0 = b2f(vb.x), v1 = b2f(vb.y), v2 = b2f(vb.z), v3 = b2f(vb.w);
  float s = v0 * as.x + v1 * as.y + v2 * as.z + v3 * as.w;
  float d = v0 * ad.x + v1 * ad.y + v2 * ad.z + v3 * ad.w;
  #pragma unroll
  for (int off = 1; off < 16; off <<= 1) {
    s += __shfl_xor(s, off);
    d += __shfl_xor(d, off);
  }
  if ((lane & 15) == 0) {
    int h = lane >> 4;
    a_src[(size_t)wid * 4 + h] = s;
    a_dst[(size_t)wid * 4 + h] = d;
  }
}

__global__ __launch_bounds__(256) void attn_coef_h1(const ushort* __restrict__ xl,
                                                    const float* __restrict__ att_src,
                                                    const float* __restrict__ att_dst,
                                                    float* __restrict__ a_src,
                                                    float* __restrict__ a_dst, int n) {
  int wid = (blockIdx.x * 256 + threadIdx.x) >> 6;
  int lane = threadIdx.x & 63;
  if (wid >= n) return;
  uint vb = *(const uint*)(xl + (size_t)wid * 128 + lane * 2);
  float2 as = *(const float2*)(att_src + lane * 2);
  float2 ad = *(const float2*)(att_dst + lane * 2);
  float v0 = b2f((ushort)(vb & 0xFFFF)), v1 = b2f((ushort)(vb >> 16));
  float s = v0 * as.x + v1 * as.y;
  float d = v0 * ad.x + v1 * ad.y;
  #pragma unroll
  for (int off = 1; off < 64; off <<= 1) {
    s += __shfl_xor(s, off);
    d += __shfl_xor(d, off);
  }
  if (lane == 0) { a_src[wid] = s; a_dst[wid] = d; }
}

// ---------------- CSR build ---------------------------------------------------
__global__ __launch_bounds__(256) void hist_k(const int* __restrict__ edst,
                                              int* __restrict__ hist, int E, int N) {
  int e = blockIdx.x * 256 + threadIdx.x;
  if (e >= E + N) return;
  int d = (e < E) ? edst[e] : (e - E);
  atomicAdd(hist + d, 1);
}

// two-level scan: per-1024-chunk scan, then chunk-sum scan, then offset add
__global__ __launch_bounds__(256) void scan1_k(const int* __restrict__ hist,
                                               int* __restrict__ excl,
                                               int* __restrict__ chunksum, int n) {
  __shared__ int sums[256];
  int base = blockIdx.x * 1024 + threadIdx.x * 4;
  int4 v = {0, 0, 0, 0};
  if (base + 3 < n) v = *(const int4*)(hist + base);
  else {
    if (base < n)     v.x = hist[base];
    if (base + 1 < n) v.y = hist[base + 1];
    if (base + 2 < n) v.z = hist[base + 2];
    if (base + 3 < n) v.w = hist[base + 3];
  }
  int s = v.x + v.y + v.z + v.w;
  sums[threadIdx.x] = s;
  __syncthreads();
  for (int off = 1; off < 256; off <<= 1) {
    int t = (threadIdx.x >= (unsigned)off) ? sums[threadIdx.x - off] : 0;
    __syncthreads();
    sums[threadIdx.x] += t;
    __syncthreads();
  }
  if (threadIdx.x == 255) chunksum[blockIdx.x] = sums[255];
  int e0 = sums[threadIdx.x] - s;
  int e1 = e0 + v.x, e2 = e1 + v.y, e3 = e2 + v.z;
  if (base + 3 < n) {
    int4 o = {e0, e1, e2, e3};
    *(int4*)(excl + base) = o;
  } else {
    if (base < n)     excl[base] = e0;
    if (base + 1 < n) excl[base + 1] = e1;
    if (base + 2 < n) excl[base + 2] = e2;
    if (base + 3 < n) excl[base + 3] = e3;
  }
}

__global__ void scan2_k(const int* __restrict__ chunksum,
                        int* __restrict__ chunkoff, int nchunks) {
  if (threadIdx.x == 0) {
    int run = 0;
    for (int c = 0; c < nchunks; ++c) { chunkoff[c] = run; run += chunksum[c]; }
  }
}

__global__ __launch_bounds__(256) void addoff_k(int* __restrict__ rowptr,
                                                int* __restrict__ cursor,
                                                const int* __restrict__ chunkoff,
                                                int n, int total) {
  int i = blockIdx.x * 256 + threadIdx.x;
  if (i == 0) rowptr[n] = total;
  if (i >= n) return;
  int r = rowptr[i] + chunkoff[i >> 10];
  rowptr[i] = r;
  cursor[i] = r;
}

__global__ __launch_bounds__(256) void scatter_k(const int* __restrict__ esrc,
                                                 const int* __restrict__ edst,
                                                 int* __restrict__ cursor,
                                                 int* __restrict__ csr_src, int E, int N) {
  int e = blockIdx.x * 256 + threadIdx.x;
  if (e >= E + N) return;
  int s = (e < E) ? esrc[e] : (e - E);
  int d = (e < E) ? edst[e] : (e - E);
  int pos = atomicAdd(cursor + d, 1);
  csr_src[pos] = s;
}

// ---------------- fused segment softmax + aggregation (wave per node) --------
template<int H, int C, bool RELU, bool OUT_BF16>
__global__ __launch_bounds__(256) void agg_csr(const int* __restrict__ rowptr,
                                               const int* __restrict__ csr_src,
                                               const float* __restrict__ a_src,
                                               const float* __restrict__ a_dst,
                                               const ushort* __restrict__ xl,
                                               const float* __restrict__ bias,
                                               void* __restrict__ out, int n) {
  constexpr int F = H * C;
  constexpr int PER = F / 64;
  int wid = (blockIdx.x * 256 + threadIdx.x) >> 6;
  int lane = threadIdx.x & 63;
  if (wid >= n) return;
  const int h = (lane * PER) / C;
  const int beg = rowptr[wid];
  const int end = rowptr[wid + 1];
  const float adh = a_dst[(size_t)wid * H + h];

  // pass 1: segment max (self-loop guarantees end > beg)
  float m = -1e30f;
  for (int j = beg; j < end; ++j) {
    int s = csr_src[j];
    float v = a_src[(size_t)s * H + h] + adh;
    v = (v > 0.f) ? v : NEG_SLOPE * v;
    m = fmaxf(m, v);
  }

  // pass 2: denom + weighted gather-accumulate (fp32 acc, bf16 gather)
  float den = 0.f;
  float acc[PER] = {};
  for (int j = beg; j < end; ++j) {
    int s = csr_src[j];
    float v = a_src[(size_t)s * H + h] + adh;
    v = (v > 0.f) ? v : NEG_SLOPE * v;
    float p = __expf(v - m);
    den += p;
    if constexpr (PER == 4) {
      ushort4 xv = *(const ushort4*)(xl + (size_t)s * F + lane * 4);
      acc[0] = fmaf(p, b2f(xv.x), acc[0]);
      acc[1] = fmaf(p, b2f(xv.y), acc[1]);
      acc[2] = fmaf(p, b2f(xv.z), acc[2]);
      acc[3] = fmaf(p, b2f(xv.w), acc[3]);
    } else {
      uint xv = *(const uint*)(xl + (size_t)s * F + lane * 2);
      acc[0] = fmaf(p, b2f((ushort)(xv & 0xFFFF)), acc[0]);
      acc[1] = fmaf(p, b2f((ushort)(xv >> 16)), acc[1]);
    }
  }

  float inv = 1.f / (den + 1e-16f);
  if constexpr (OUT_BF16) {
    ushort* od = (ushort*)out + (size_t)wid * F + lane * PER;
    float o[PER];
    #pragma unroll
    for (int i = 0; i < PER; ++i) o[i] = acc[i] * inv;
    if constexpr (RELU) {
      #pragma unroll
      for (int i = 0; i < PER; ++i) o[i] = fmaxf(o[i] + bias[lane * PER + i], 0.f);
    }
    if constexpr (PER == 4) {
      ushort4 ov = {f2b(o[0]), f2b(o[1]), f2b(o[2]), f2b(o[3])};
      *(ushort4*)od = ov;
    } else {
      uint ov = (uint)f2b(o[0]) | ((uint)f2b(o[1]) << 16);
      *(uint*)od = ov;
    }
  } else {
    float* od = (float*)out + (size_t)wid * F + lane * PER;
    if constexpr (PER == 4) {
      float4 ov = {acc[0] * inv, acc[1] * inv, acc[2] * inv, acc[3] * inv};
      *(float4*)od = ov;
    } else {
      float2 ov = {acc[0] * inv, acc[1] * inv};
      *(float2*)od = ov;
    }
  }
}

// ---------------- global mean pool (batch sorted) ----------------------------
__global__ __launch_bounds__(256) void pool_k(const float* __restrict__ h,
                                              const int* __restrict__ batch,
                                              float* __restrict__ pool, int n) {
  int ch = threadIdx.x & 127;
  int half = threadIdx.x >> 7;
  int n0 = blockIdx.x * 256;
  float run = 0.f;
  int curg = -1;
  for (int r = half; r < 256; r += 2) {
    int node = n0 + r;
    if (node >= n) break;
    int g = batch[node];
    if (g != curg) {
      if (curg >= 0) unsafeAtomicAdd(pool + curg * 128 + ch, run);
      run = 0.f;
      curg = g;
    }
    run += h[(size_t)node * 128 + ch];
  }
  if (curg >= 0) unsafeAtomicAdd(pool + curg * 128 + ch, run);
}

__global__ __launch_bounds__(256) void finalize_k(const float* __restrict__ pool,
                                                  const int* __restrict__ batch,
                                                  const float* __restrict__ bias2,
                                                  float* __restrict__ out, int n) {
  int t = blockIdx.x * 256 + threadIdx.x;
  if (t >= 8 * 128) return;
  int g = t >> 7, c = t & 127;
  int a = 0, b = n;
  while (a < b) { int mid = (a + b) >> 1; if (batch[mid] < g) a = mid + 1; else b = mid; }
  int lo = a;
  b = n;
  while (a < b) { int mid = (a + b) >> 1; if (batch[mid] < g + 1) a = mid + 1; else b = mid; }
  int hi = a;
  float cnt = (float)(hi - lo);
  out[t] = pool[t] / fmaxf(cnt, 1.f) + bias2[c];
}

extern "C" void kernel_launch(void* const* d_in, const int* in_sizes, int n_in,
                              void* d_out, int out_size, void* d_ws, size_t ws_size,
                              hipStream_t stream) {
  const float* x        = (const float*)d_in[0];
  const int*   ei       = (const int*)d_in[1];
  const int*   batch    = (const int*)d_in[2];
  const float* W1       = (const float*)d_in[3];
  const float* att_src1 = (const float*)d_in[4];
  const float* att_dst1 = (const float*)d_in[5];
  const float* bias1    = (const float*)d_in[6];
  const float* W2       = (const float*)d_in[7];
  const float* att_src2 = (const float*)d_in[8];
  const float* att_dst2 = (const float*)d_in[9];
  const float* bias2    = (const float*)d_in[10];
  float* out = (float*)d_out;

  const int E  = in_sizes[1] / 2;
  const int NN = in_sizes[2];
  const int ET = E + NN;
  const int* esrc = ei;
  const int* edst = ei + E;

  // ---- workspace layout (~70 MB, 256B-aligned chunks) ----
  char* w = (char*)d_ws;
  size_t woff = 0;
  auto walloc = [&](size_t bytes) -> char* {
    char* r = w + woff;
    woff += (bytes + 255) & ~(size_t)255;
    return r;
  };
  ushort* xbuf   = (ushort*)walloc((size_t)NN * 128 * 2);  // x_bf; later xl2_bf
  ushort* xl1    = (ushort*)walloc((size_t)NN * 256 * 2);  // xl1_bf; later out2 (f32, NN*128)
  ushort* h1     = (ushort*)walloc((size_t)NN * 256 * 2);
  float*  a_src1 = (float*)walloc((size_t)NN * 4 * 4);
  float*  a_dst1 = (float*)walloc((size_t)NN * 4 * 4);
  float*  a_src2 = (float*)walloc((size_t)NN * 4);
  float*  a_dst2 = (float*)walloc((size_t)NN * 4);
  int*    rowptr = (int*)walloc((size_t)(NN + 1) * 4);
  int*    cursor = (int*)walloc((size_t)NN * 4);
  int*    hist   = (int*)walloc((size_t)NN * 4);
  int*    csrsrc = (int*)walloc((size_t)ET * 4);
  ushort* Bp1    = (ushort*)walloc(128 * 256 * 2);
  ushort* Bp2    = (ushort*)walloc(256 * 128 * 2);
  int*    chunks = (int*)walloc(256 * 4);
  int*    chunko = (int*)walloc(256 * 4);
  float*  pool   = (float*)walloc(8 * 128 * 4);
  ushort* xl2    = xbuf;                 // NN*128 bf16 (x_bf dead after gemm1)
  float*  out2   = (float*)xl1;          // NN*128 f32  (xl1 dead after agg1)

  dim3 blk(256);
  const int nbE = (ET + 255) / 256;
  const int nbN4 = (NN + 3) / 4;
  const int nchunks = (NN + 1023) / 1024;
  const int gblocks = (NN / 16 + 3) / 4;   // NN divisible by 16 (50000)

  // ---- CSR build ----
  hipMemsetAsync(hist, 0, (size_t)NN * 4, stream);
  hipMemsetAsync(pool, 0, 8 * 128 * 4, stream);
  hist_k<<<nbE, blk, 0, stream>>>(edst, hist, E, NN);
  scan1_k<<<nchunks, blk, 0, stream>>>(hist, rowptr, chunks, NN);
  scan2_k<<<1, 64, 0, stream>>>(chunks, chunko, nchunks);
  addoff_k<<<(NN + 255) / 256, blk, 0, stream>>>(rowptr, cursor, chunko, NN, ET);
  scatter_k<<<nbE, blk, 0, stream>>>(esrc, edst, cursor, csrsrc, E, NN);

  // ---- dtype conversions / weight packing ----
  conv_bf16<<<((size_t)NN * 128 / 4 + 255) / 256, blk, 0, stream>>>(x, xbuf, (size_t)NN * 128);
  pack_w<<<(128 * 256 + 255) / 256, blk, 0, stream>>>(W1, Bp1, 128, 256);
  pack_w<<<(256 * 128 + 255) / 256, blk, 0, stream>>>(W2, Bp2, 256, 128);

  // ---- layer 1 ----
  gemm_mfma<256, 128><<<gblocks, blk, 0, stream>>>(xbuf, Bp1, xl1, NN);
  attn_coef_h4<<<nbN4, blk, 0, stream>>>(xl1, att_src1, att_dst1, a_src1, a_dst1, NN);
  agg_csr<4, 64, true, true><<<nbN4, blk, 0, stream>>>(rowptr, csrsrc, a_src1, a_dst1,
                                                       xl1, bias1, h1, NN);

  // ---- layer 2 ----
  gemm_mfma<128, 256><<<gblocks, blk, 0, stream>>>(h1, Bp2, xl2, NN);
  attn_coef_h1<<<nbN4, blk, 0, stream>>>(xl2, att_src2, att_dst2, a_src2, a_dst2, NN);
  agg_csr<1, 128, false, false><<<nbN4, blk, 0, stream>>>(rowptr, csrsrc, a_src2, a_dst2,
                                                          xl2, nullptr, out2, NN);

  // ---- pool + finalize ----
  pool_k<<<(NN + 255) / 256, blk, 0, stream>>>(out2, batch, pool, NN);
  finalize_k<<<4, blk, 0, stream>>>(pool, batch, bias2, out, NN);
}

// Round 4
// 390.782 us; speedup vs baseline: 10.5837x; 1.2963x over previous
//
#include <hip/hip_runtime.h>
#include <cstdint>
#include <cstddef>

#define NEG_SLOPE 0.2f

typedef __attribute__((ext_vector_type(8))) short bf16x8;
typedef __attribute__((ext_vector_type(4))) float f32x4;

__device__ __forceinline__ ushort f2b(float f) {   // fp32 -> bf16 RNE
  unsigned u = __float_as_uint(f);
  return (ushort)((u + 0x7FFFu + ((u >> 16) & 1)) >> 16);
}
__device__ __forceinline__ float b2f(ushort b) {
  return __uint_as_float(((unsigned)b) << 16);
}

// ---------------- fp32 -> bf16 conversion ------------------------------------
__global__ __launch_bounds__(256) void conv_bf16(const float* __restrict__ in,
                                                 ushort* __restrict__ out, size_t total) {
  size_t i = ((size_t)blockIdx.x * 256 + threadIdx.x) * 4;
  if (i + 3 < total) {
    float4 v = *(const float4*)(in + i);
    ushort4 o = {f2b(v.x), f2b(v.y), f2b(v.z), f2b(v.w)};
    *(ushort4*)(out + i) = o;
  } else {
    for (; i < total; ++i) out[i] = f2b(in[i]);
  }
}

// ---------------- pack W[K][N] fp32 -> bf16 [K/8][N][8] ----------------------
__global__ __launch_bounds__(256) void pack_w(const float* __restrict__ W,
                                              ushort* __restrict__ Bp, int K, int N) {
  int i = blockIdx.x * 256 + threadIdx.x;
  if (i >= K * N) return;
  int k = i / N, n = i % N;
  Bp[((size_t)(k >> 3) * N + n) * 8 + (k & 7)] = f2b(W[i]);
}

// ---------------- bf16 MFMA GEMM: C[MxN] = A[MxK] @ B[KxN] -------------------
template<int N, int K>
__global__ __launch_bounds__(256) void gemm_mfma(const ushort* __restrict__ A,
                                                 const ushort* __restrict__ Bp,
                                                 ushort* __restrict__ C, int M) {
  const int wave = threadIdx.x >> 6;
  const int lane = threadIdx.x & 63;
  const int strips = M / 16;
  const int strip = blockIdx.x * 4 + wave;
  if (strip >= strips) return;
  const int r = lane & 15, kg = lane >> 4;
  const int row = strip * 16 + r;

  bf16x8 a[K / 32];
  #pragma unroll
  for (int k0 = 0; k0 < K / 32; ++k0)
    a[k0] = *(const bf16x8*)(A + (size_t)row * K + k0 * 32 + kg * 8);

  #pragma unroll 2
  for (int n0 = 0; n0 < N / 16; ++n0) {
    f32x4 acc = {0.f, 0.f, 0.f, 0.f};
    #pragma unroll
    for (int k0 = 0; k0 < K / 32; ++k0) {
      bf16x8 b = *(const bf16x8*)(Bp + ((size_t)(k0 * 4 + kg) * N + n0 * 16 + r) * 8);
      acc = __builtin_amdgcn_mfma_f32_16x16x32_bf16(a[k0], b, acc, 0, 0, 0);
    }
    #pragma unroll
    for (int i = 0; i < 4; ++i)
      C[((size_t)strip * 16 + kg * 4 + i) * N + n0 * 16 + r] = f2b(acc[i]);
  }
}

// ---------------- per-node attention coefficients (bf16 xl) ------------------
__global__ __launch_bounds__(256) void attn_coef_h4(const ushort* __restrict__ xl,
                                                    const float* __restrict__ att_src,
                                                    const float* __restrict__ att_dst,
                                                    float* __restrict__ a_src,
                                                    float* __restrict__ a_dst, int n) {
  int wid = (blockIdx.x * 256 + threadIdx.x) >> 6;
  int lane = threadIdx.x & 63;
  if (wid >= n) return;
  ushort4 vb = *(const ushort4*)(xl + (size_t)wid * 256 + lane * 4);
  float4 as = *(const float4*)(att_src + lane * 4);
  float4 ad = *(const float4*)(att_dst + lane * 4);
  float v0 = b2f(vb.x), v1 = b2f(vb.y), v2 = b2f(vb.z), v3 = b2f(vb.w);
  float s = v0 * as.x + v1 * as.y + v2 * as.z + v3 * as.w;
  float d = v0 * ad.x + v1 * ad.y + v2 * ad.z + v3 * ad.w;
  #pragma unroll
  for (int off = 1; off < 16; off <<= 1) {
    s += __shfl_xor(s, off);
    d += __shfl_xor(d, off);
  }
  if ((lane & 15) == 0) {
    int h = lane >> 4;
    a_src[(size_t)wid * 4 + h] = s;
    a_dst[(size_t)wid * 4 + h] = d;
  }
}

__global__ __launch_bounds__(256) void attn_coef_h1(const ushort* __restrict__ xl,
                                                    const float* __restrict__ att_src,
                                                    const float* __restrict__ att_dst,
                                                    float* __restrict__ a_src,
                                                    float* __restrict__ a_dst, int n) {
  int wid = (blockIdx.x * 256 + threadIdx.x) >> 6;
  int lane = threadIdx.x & 63;
  if (wid >= n) return;
  uint vb = *(const uint*)(xl + (size_t)wid * 128 + lane * 2);
  float2 as = *(const float2*)(att_src + lane * 2);
  float2 ad = *(const float2*)(att_dst + lane * 2);
  float v0 = b2f((ushort)(vb & 0xFFFF)), v1 = b2f((ushort)(vb >> 16));
  float s = v0 * as.x + v1 * as.y;
  float d = v0 * ad.x + v1 * ad.y;
  #pragma unroll
  for (int off = 1; off < 64; off <<= 1) {
    s += __shfl_xor(s, off);
    d += __shfl_xor(d, off);
  }
  if (lane == 0) { a_src[wid] = s; a_dst[wid] = d; }
}

// ---------------- CSR build ---------------------------------------------------
__global__ __launch_bounds__(256) void hist_k(const int* __restrict__ edst,
                                              int* __restrict__ hist, int E, int N) {
  int e = blockIdx.x * 256 + threadIdx.x;
  if (e >= E + N) return;
  int d = (e < E) ? edst[e] : (e - E);
  atomicAdd(hist + d, 1);
}

__global__ __launch_bounds__(256) void scan1_k(const int* __restrict__ hist,
                                               int* __restrict__ excl,
                                               int* __restrict__ chunksum, int n) {
  __shared__ int sums[256];
  int base = blockIdx.x * 1024 + threadIdx.x * 4;
  int4 v = {0, 0, 0, 0};
  if (base + 3 < n) v = *(const int4*)(hist + base);
  else {
    if (base < n)     v.x = hist[base];
    if (base + 1 < n) v.y = hist[base + 1];
    if (base + 2 < n) v.z = hist[base + 2];
    if (base + 3 < n) v.w = hist[base + 3];
  }
  int s = v.x + v.y + v.z + v.w;
  sums[threadIdx.x] = s;
  __syncthreads();
  for (int off = 1; off < 256; off <<= 1) {
    int t = (threadIdx.x >= (unsigned)off) ? sums[threadIdx.x - off] : 0;
    __syncthreads();
    sums[threadIdx.x] += t;
    __syncthreads();
  }
  if (threadIdx.x == 255) chunksum[blockIdx.x] = sums[255];
  int e0 = sums[threadIdx.x] - s;
  int e1 = e0 + v.x, e2 = e1 + v.y, e3 = e2 + v.z;
  if (base + 3 < n) {
    int4 o = {e0, e1, e2, e3};
    *(int4*)(excl + base) = o;
  } else {
    if (base < n)     excl[base] = e0;
    if (base + 1 < n) excl[base + 1] = e1;
    if (base + 2 < n) excl[base + 2] = e2;
    if (base + 3 < n) excl[base + 3] = e3;
  }
}

__global__ void scan2_k(const int* __restrict__ chunksum,
                        int* __restrict__ chunkoff, int nchunks) {
  if (threadIdx.x == 0) {
    int run = 0;
    for (int c = 0; c < nchunks; ++c) { chunkoff[c] = run; run += chunksum[c]; }
  }
}

__global__ __launch_bounds__(256) void addoff_k(int* __restrict__ rowptr,
                                                int* __restrict__ cursor,
                                                const int* __restrict__ chunkoff,
                                                int n, int total) {
  int i = blockIdx.x * 256 + threadIdx.x;
  if (i == 0) rowptr[n] = total;
  if (i >= n) return;
  int r = rowptr[i] + chunkoff[i >> 10];
  rowptr[i] = r;
  cursor[i] = r;
}

__global__ __launch_bounds__(256) void scatter_k(const int* __restrict__ esrc,
                                                 const int* __restrict__ edst,
                                                 int* __restrict__ cursor,
                                                 int* __restrict__ csr_src, int E, int N) {
  int e = blockIdx.x * 256 + threadIdx.x;
  if (e >= E + N) return;
  int s = (e < E) ? esrc[e] : (e - E);
  int d = (e < E) ? edst[e] : (e - E);
  int pos = atomicAdd(cursor + d, 1);
  csr_src[pos] = s;
}

// ---------------- fused segment softmax + aggregation (wave per node) --------
// Phase A: lane-parallel online-softmax stats (64/H edge slots x H heads),
//          merged via shfl_xor.
// Phase B: gather unrolled by U=8 with masked tail groups (>=8 loads in flight).
template<int H, int C, bool RELU, bool OUT_BF16>
__global__ __launch_bounds__(256) void agg_csr2(const int* __restrict__ rowptr,
                                                const int* __restrict__ csr_src,
                                                const float* __restrict__ a_src,
                                                const float* __restrict__ a_dst,
                                                const ushort* __restrict__ xl,
                                                const float* __restrict__ bias,
                                                void* __restrict__ out, int n) {
  constexpr int F = H * C;
  constexpr int PER = F / 64;
  constexpr int NSLOT = 64 / H;
  constexpr int U = 8;
  int wid = (blockIdx.x * 256 + threadIdx.x) >> 6;
  int lane = threadIdx.x & 63;
  if (wid >= n) return;
  const int beg = rowptr[wid];
  const int end = rowptr[wid + 1];

  // ---- phase A: per-head (m, den) via online softmax + shuffle merge ----
  const int hs = lane & (H - 1);
  const int slot = lane >> (H == 4 ? 2 : 0);
  const float adhs = a_dst[(size_t)wid * H + hs];
  float m = -1e30f, d = 0.f;
  for (int j = beg + slot; j < end; j += NSLOT) {
    int s = csr_src[j];
    float v = a_src[(size_t)s * H + hs] + adhs;
    v = (v > 0.f) ? v : NEG_SLOPE * v;
    float mn = fmaxf(m, v);
    d = d * __expf(m - mn) + __expf(v - mn);
    m = mn;
  }
  #pragma unroll
  for (int off = H; off < 64; off <<= 1) {
    float mo = __shfl_xor(m, off);
    float dd = __shfl_xor(d, off);
    float mn = fmaxf(m, mo);
    d = d * __expf(m - mn) + dd * __expf(mo - mn);
    m = mn;
  }
  // lane L holds reduced stats for head L&(H-1); fetch stats for gather head
  const int h = (lane * PER) / C;          // this lane's head in phase B
  const float mB = __shfl(m, h);
  const float invDen = 1.f / (__shfl(d, h) + 1e-16f);
  const float adh = __shfl(adhs, h);

  // ---- phase B: weighted gather-accumulate, groups of U with masking ----
  float acc[PER] = {};
  const ushort* xb = xl + lane * PER;
  for (int j = beg; j < end; j += U) {
    int s[U];
    #pragma unroll
    for (int u = 0; u < U; ++u) {
      int jj = j + u;
      s[u] = (jj < end) ? csr_src[jj] : wid;   // own row = always-valid dummy
    }
    if constexpr (PER == 4) {
      ushort4 xv[U];
      #pragma unroll
      for (int u = 0; u < U; ++u) xv[u] = *(const ushort4*)(xb + (size_t)s[u] * F);
      float p[U];
      #pragma unroll
      for (int u = 0; u < U; ++u) {
        float v = a_src[(size_t)s[u] * H + h] + adh;
        v = (v > 0.f) ? v : NEG_SLOPE * v;
        p[u] = (j + u < end) ? __expf(v - mB) : 0.f;
      }
      #pragma unroll
      for (int u = 0; u < U; ++u) {
        acc[0] = fmaf(p[u], b2f(xv[u].x), acc[0]);
        acc[1] = fmaf(p[u], b2f(xv[u].y), acc[1]);
        acc[2] = fmaf(p[u], b2f(xv[u].z), acc[2]);
        acc[3] = fmaf(p[u], b2f(xv[u].w), acc[3]);
      }
    } else {
      uint xv[U];
      #pragma unroll
      for (int u = 0; u < U; ++u) xv[u] = *(const uint*)(xb + (size_t)s[u] * F);
      float p[U];
      #pragma unroll
      for (int u = 0; u < U; ++u) {
        float v = a_src[(size_t)s[u] * H + h] + adh;
        v = (v > 0.f) ? v : NEG_SLOPE * v;
        p[u] = (j + u < end) ? __expf(v - mB) : 0.f;
      }
      #pragma unroll
      for (int u = 0; u < U; ++u) {
        acc[0] = fmaf(p[u], b2f((ushort)(xv[u] & 0xFFFF)), acc[0]);
        acc[1] = fmaf(p[u], b2f((ushort)(xv[u] >> 16)), acc[1]);
      }
    }
  }

  // ---- epilogue ----
  if constexpr (OUT_BF16) {
    ushort* od = (ushort*)out + (size_t)wid * F + lane * PER;
    float o[PER];
    #pragma unroll
    for (int i = 0; i < PER; ++i) o[i] = acc[i] * invDen;
    if constexpr (RELU) {
      #pragma unroll
      for (int i = 0; i < PER; ++i) o[i] = fmaxf(o[i] + bias[lane * PER + i], 0.f);
    }
    if constexpr (PER == 4) {
      ushort4 ov = {f2b(o[0]), f2b(o[1]), f2b(o[2]), f2b(o[3])};
      *(ushort4*)od = ov;
    } else {
      uint ov = (uint)f2b(o[0]) | ((uint)f2b(o[1]) << 16);
      *(uint*)od = ov;
    }
  } else {
    float* od = (float*)out + (size_t)wid * F + lane * PER;
    if constexpr (PER == 4) {
      float4 ov = {acc[0] * invDen, acc[1] * invDen, acc[2] * invDen, acc[3] * invDen};
      *(float4*)od = ov;
    } else {
      float2 ov = {acc[0] * invDen, acc[1] * invDen};
      *(float2*)od = ov;
    }
  }
}

// ---------------- global mean pool (batch sorted) ----------------------------
__global__ __launch_bounds__(256) void pool_k(const float* __restrict__ h,
                                              const int* __restrict__ batch,
                                              float* __restrict__ pool, int n) {
  int ch = threadIdx.x & 127;
  int half = threadIdx.x >> 7;
  int n0 = blockIdx.x * 256;
  float run = 0.f;
  int curg = -1;
  for (int r = half; r < 256; r += 2) {
    int node = n0 + r;
    if (node >= n) break;
    int g = batch[node];
    if (g != curg) {
      if (curg >= 0) unsafeAtomicAdd(pool + curg * 128 + ch, run);
      run = 0.f;
      curg = g;
    }
    run += h[(size_t)node * 128 + ch];
  }
  if (curg >= 0) unsafeAtomicAdd(pool + curg * 128 + ch, run);
}

__global__ __launch_bounds__(256) void finalize_k(const float* __restrict__ pool,
                                                  const int* __restrict__ batch,
                                                  const float* __restrict__ bias2,
                                                  float* __restrict__ out, int n) {
  int t = blockIdx.x * 256 + threadIdx.x;
  if (t >= 8 * 128) return;
  int g = t >> 7, c = t & 127;
  int a = 0, b = n;
  while (a < b) { int mid = (a + b) >> 1; if (batch[mid] < g) a = mid + 1; else b = mid; }
  int lo = a;
  b = n;
  while (a < b) { int mid = (a + b) >> 1; if (batch[mid] < g + 1) a = mid + 1; else b = mid; }
  int hi = a;
  float cnt = (float)(hi - lo);
  out[t] = pool[t] / fmaxf(cnt, 1.f) + bias2[c];
}

extern "C" void kernel_launch(void* const* d_in, const int* in_sizes, int n_in,
                              void* d_out, int out_size, void* d_ws, size_t ws_size,
                              hipStream_t stream) {
  const float* x        = (const float*)d_in[0];
  const int*   ei       = (const int*)d_in[1];
  const int*   batch    = (const int*)d_in[2];
  const float* W1       = (const float*)d_in[3];
  const float* att_src1 = (const float*)d_in[4];
  const float* att_dst1 = (const float*)d_in[5];
  const float* bias1    = (const float*)d_in[6];
  const float* W2       = (const float*)d_in[7];
  const float* att_src2 = (const float*)d_in[8];
  const float* att_dst2 = (const float*)d_in[9];
  const float* bias2    = (const float*)d_in[10];
  float* out = (float*)d_out;

  const int E  = in_sizes[1] / 2;
  const int NN = in_sizes[2];
  const int ET = E + NN;
  const int* esrc = ei;
  const int* edst = ei + E;

  // ---- workspace layout ----
  char* w = (char*)d_ws;
  size_t woff = 0;
  auto walloc = [&](size_t bytes) -> char* {
    char* r = w + woff;
    woff += (bytes + 255) & ~(size_t)255;
    return r;
  };
  ushort* xbuf   = (ushort*)walloc((size_t)NN * 128 * 2);  // x_bf; later xl2_bf
  ushort* xl1    = (ushort*)walloc((size_t)NN * 256 * 2);  // xl1_bf; later out2 (f32)
  ushort* h1     = (ushort*)walloc((size_t)NN * 256 * 2);
  float*  a_src1 = (float*)walloc((size_t)NN * 4 * 4);
  float*  a_dst1 = (float*)walloc((size_t)NN * 4 * 4);
  float*  a_src2 = (float*)walloc((size_t)NN * 4);
  float*  a_dst2 = (float*)walloc((size_t)NN * 4);
  int*    rowptr = (int*)walloc((size_t)(NN + 1) * 4);
  int*    cursor = (int*)walloc((size_t)NN * 4);
  int*    hist   = (int*)walloc((size_t)NN * 4);
  int*    csrsrc = (int*)walloc((size_t)ET * 4);
  ushort* Bp1    = (ushort*)walloc(128 * 256 * 2);
  ushort* Bp2    = (ushort*)walloc(256 * 128 * 2);
  int*    chunks = (int*)walloc(256 * 4);
  int*    chunko = (int*)walloc(256 * 4);
  float*  pool   = (float*)walloc(8 * 128 * 4);
  ushort* xl2    = xbuf;
  float*  out2   = (float*)xl1;

  dim3 blk(256);
  const int nbE = (ET + 255) / 256;
  const int nbN4 = (NN + 3) / 4;
  const int nchunks = (NN + 1023) / 1024;
  const int gblocks = (NN / 16 + 3) / 4;

  // ---- CSR build ----
  hipMemsetAsync(hist, 0, (size_t)NN * 4, stream);
  hipMemsetAsync(pool, 0, 8 * 128 * 4, stream);
  hist_k<<<nbE, blk, 0, stream>>>(edst, hist, E, NN);
  scan1_k<<<nchunks, blk, 0, stream>>>(hist, rowptr, chunks, NN);
  scan2_k<<<1, 64, 0, stream>>>(chunks, chunko, nchunks);
  addoff_k<<<(NN + 255) / 256, blk, 0, stream>>>(rowptr, cursor, chunko, NN, ET);
  scatter_k<<<nbE, blk, 0, stream>>>(esrc, edst, cursor, csrsrc, E, NN);

  // ---- dtype conversions / weight packing ----
  conv_bf16<<<((size_t)NN * 128 / 4 + 255) / 256, blk, 0, stream>>>(x, xbuf, (size_t)NN * 128);
  pack_w<<<(128 * 256 + 255) / 256, blk, 0, stream>>>(W1, Bp1, 128, 256);
  pack_w<<<(256 * 128 + 255) / 256, blk, 0, stream>>>(W2, Bp2, 256, 128);

  // ---- layer 1 ----
  gemm_mfma<256, 128><<<gblocks, blk, 0, stream>>>(xbuf, Bp1, xl1, NN);
  attn_coef_h4<<<nbN4, blk, 0, stream>>>(xl1, att_src1, att_dst1, a_src1, a_dst1, NN);
  agg_csr2<4, 64, true, true><<<nbN4, blk, 0, stream>>>(rowptr, csrsrc, a_src1, a_dst1,
                                                        xl1, bias1, h1, NN);

  // ---- layer 2 ----
  gemm_mfma<128, 256><<<gblocks, blk, 0, stream>>>(h1, Bp2, xl2, NN);
  attn_coef_h1<<<nbN4, blk, 0, stream>>>(xl2, att_src2, att_dst2, a_src2, a_dst2, NN);
  agg_csr2<1, 128, false, false><<<nbN4, blk, 0, stream>>>(rowptr, csrsrc, a_src2, a_dst2,
                                                           xl2, nullptr, out2, NN);

  // ---- pool + finalize ----
  pool_k<<<(NN + 255) / 256, blk, 0, stream>>>(out2, batch, pool, NN);
  finalize_k<<<4, blk, 0, stream>>>(pool, batch, bias2, out, NN);
}

// Round 5
// 336.415 us; speedup vs baseline: 12.2941x; 1.1616x over previous
//
#include <hip/hip_runtime.h>
#include <cstdint>
#include <cstddef>

#define NEG_SLOPE 0.2f

typedef __attribute__((ext_vector_type(8))) short bf16x8;
typedef __attribute__((ext_vector_type(4))) float f32x4;

__device__ __forceinline__ ushort f2b(float f) {   // fp32 -> bf16 RNE
  unsigned u = __float_as_uint(f);
  return (ushort)((u + 0x7FFFu + ((u >> 16) & 1)) >> 16);
}
__device__ __forceinline__ float b2f(ushort b) {
  return __uint_as_float(((unsigned)b) << 16);
}

// ---------------- pack W[K][N] fp32 -> bf16 [K/8][N][8] ----------------------
__global__ __launch_bounds__(256) void pack_w(const float* __restrict__ W,
                                              ushort* __restrict__ Bp, int K, int N) {
  int i = blockIdx.x * 256 + threadIdx.x;
  if (i >= K * N) return;
  int k = i / N, n = i % N;
  Bp[((size_t)(k >> 3) * N + n) * 8 + (k & 7)] = f2b(W[i]);
}

// ---------------- bf16 MFMA GEMM + fused attention coefficients --------------
// C[MxN] = A[MxK] @ B[KxN]; also writes a_src/a_dst[M][H] = xl . att (f32 acc).
// A: f32 (AF32, converted in-register) or bf16 row-major. Bp packed [K/8][N][8].
// Wave per 16-row strip. Frag: A row=lane&15, k=(lane>>4)*8+j; B col=lane&15,
// same k; C/D col=lane&15, row=(lane>>4)*4+i.
template<int N, int K, int C, int H, bool AF32>
__global__ __launch_bounds__(256) void gemm_attn(const void* __restrict__ A_,
                                                 const ushort* __restrict__ Bp,
                                                 const float* __restrict__ att_src,
                                                 const float* __restrict__ att_dst,
                                                 ushort* __restrict__ Cc,
                                                 float* __restrict__ a_src,
                                                 float* __restrict__ a_dst, int M) {
  const int wave = threadIdx.x >> 6;
  const int lane = threadIdx.x & 63;
  const int strips = M / 16;
  const int strip = blockIdx.x * 4 + wave;
  if (strip >= strips) return;
  const int r = lane & 15, kg = lane >> 4;
  const int row = strip * 16 + r;

  bf16x8 a[K / 32];
  if constexpr (AF32) {
    const float* Af = (const float*)A_;
    #pragma unroll
    for (int k0 = 0; k0 < K / 32; ++k0) {
      float4 f0 = *(const float4*)(Af + (size_t)row * K + k0 * 32 + kg * 8);
      float4 f1 = *(const float4*)(Af + (size_t)row * K + k0 * 32 + kg * 8 + 4);
      bf16x8 t;
      t[0] = (short)f2b(f0.x); t[1] = (short)f2b(f0.y);
      t[2] = (short)f2b(f0.z); t[3] = (short)f2b(f0.w);
      t[4] = (short)f2b(f1.x); t[5] = (short)f2b(f1.y);
      t[6] = (short)f2b(f1.z); t[7] = (short)f2b(f1.w);
      a[k0] = t;
    }
  } else {
    const ushort* Ab = (const ushort*)A_;
    #pragma unroll
    for (int k0 = 0; k0 < K / 32; ++k0)
      a[k0] = *(const bf16x8*)(Ab + (size_t)row * K + k0 * 32 + kg * 8);
  }

  float as_part[4] = {}, ad_part[4] = {};
  #pragma unroll 2
  for (int n0 = 0; n0 < N / 16; ++n0) {
    f32x4 acc = {0.f, 0.f, 0.f, 0.f};
    #pragma unroll
    for (int k0 = 0; k0 < K / 32; ++k0) {
      bf16x8 b = *(const bf16x8*)(Bp + ((size_t)(k0 * 4 + kg) * N + n0 * 16 + r) * 8);
      acc = __builtin_amdgcn_mfma_f32_16x16x32_bf16(a[k0], b, acc, 0, 0, 0);
    }
    // attention partial dot: reduce acc[i]*att[col] over the 16 r-lanes
    float asv = att_src[n0 * 16 + r];
    float adv = att_dst[n0 * 16 + r];
    #pragma unroll
    for (int i = 0; i < 4; ++i) {
      float ts = acc[i] * asv;
      float td = acc[i] * adv;
      #pragma unroll
      for (int off = 1; off < 16; off <<= 1) {
        ts += __shfl_xor(ts, off);
        td += __shfl_xor(td, off);
      }
      as_part[i] += ts;
      ad_part[i] += td;
    }
    // store C tile
    #pragma unroll
    for (int i = 0; i < 4; ++i)
      Cc[((size_t)strip * 16 + kg * 4 + i) * N + n0 * 16 + r] = f2b(acc[i]);
    // head column-block complete -> write a_src/a_dst
    if (((n0 + 1) * 16) % C == 0) {
      int h = (n0 * 16) / C;
      #pragma unroll
      for (int i = 0; i < 4; ++i) {
        if (r == i) {
          a_src[(size_t)(strip * 16 + kg * 4 + i) * H + h] = as_part[i];
          a_dst[(size_t)(strip * 16 + kg * 4 + i) * H + h] = ad_part[i];
        }
        as_part[i] = 0.f;
        ad_part[i] = 0.f;
      }
    }
  }
}

// ---------------- CSR build ---------------------------------------------------
__global__ __launch_bounds__(256) void hist_k(const int* __restrict__ edst,
                                              int* __restrict__ hist, int E, int N) {
  int e = blockIdx.x * 256 + threadIdx.x;
  if (e >= E + N) return;
  int d = (e < E) ? edst[e] : (e - E);
  atomicAdd(hist + d, 1);
}

__global__ __launch_bounds__(256) void scan1_k(const int* __restrict__ hist,
                                               int* __restrict__ excl,
                                               int* __restrict__ chunksum, int n) {
  __shared__ int sums[256];
  int base = blockIdx.x * 1024 + threadIdx.x * 4;
  int4 v = {0, 0, 0, 0};
  if (base + 3 < n) v = *(const int4*)(hist + base);
  else {
    if (base < n)     v.x = hist[base];
    if (base + 1 < n) v.y = hist[base + 1];
    if (base + 2 < n) v.z = hist[base + 2];
    if (base + 3 < n) v.w = hist[base + 3];
  }
  int s = v.x + v.y + v.z + v.w;
  sums[threadIdx.x] = s;
  __syncthreads();
  for (int off = 1; off < 256; off <<= 1) {
    int t = (threadIdx.x >= (unsigned)off) ? sums[threadIdx.x - off] : 0;
    __syncthreads();
    sums[threadIdx.x] += t;
    __syncthreads();
  }
  if (threadIdx.x == 255) chunksum[blockIdx.x] = sums[255];
  int e0 = sums[threadIdx.x] - s;
  int e1 = e0 + v.x, e2 = e1 + v.y, e3 = e2 + v.z;
  if (base + 3 < n) {
    int4 o = {e0, e1, e2, e3};
    *(int4*)(excl + base) = o;
  } else {
    if (base < n)     excl[base] = e0;
    if (base + 1 < n) excl[base + 1] = e1;
    if (base + 2 < n) excl[base + 2] = e2;
    if (base + 3 < n) excl[base + 3] = e3;
  }
}

__global__ void scan2_k(const int* __restrict__ chunksum,
                        int* __restrict__ chunkoff, int nchunks) {
  if (threadIdx.x == 0) {
    int run = 0;
    for (int c = 0; c < nchunks; ++c) { chunkoff[c] = run; run += chunksum[c]; }
  }
}

__global__ __launch_bounds__(256) void addoff_k(int* __restrict__ rowptr,
                                                int* __restrict__ cursor,
                                                const int* __restrict__ chunkoff,
                                                int n, int total) {
  int i = blockIdx.x * 256 + threadIdx.x;
  if (i == 0) rowptr[n] = total;
  if (i >= n) return;
  int r = rowptr[i] + chunkoff[i >> 10];
  rowptr[i] = r;
  cursor[i] = r;
}

__global__ __launch_bounds__(256) void scatter_k(const int* __restrict__ esrc,
                                                 const int* __restrict__ edst,
                                                 int* __restrict__ cursor,
                                                 int* __restrict__ csr_src, int E, int N) {
  int e = blockIdx.x * 256 + threadIdx.x;
  if (e >= E + N) return;
  int s = (e < E) ? esrc[e] : (e - E);
  int d = (e < E) ? edst[e] : (e - E);
  int pos = atomicAdd(cursor + d, 1);
  csr_src[pos] = s;
}

// ---------------- single-pass flash-style segment softmax + aggregation ------
// Wave per node; groups of U=8 edges; running-max rescale per group (exact).
template<int H, int C, bool RELU, bool OUT_BF16>
__global__ __launch_bounds__(256) void agg_flash(const int* __restrict__ rowptr,
                                                 const int* __restrict__ csr_src,
                                                 const float* __restrict__ a_src,
                                                 const float* __restrict__ a_dst,
                                                 const ushort* __restrict__ xl,
                                                 const float* __restrict__ bias,
                                                 void* __restrict__ out, int n) {
  constexpr int F = H * C;
  constexpr int PER = F / 64;
  constexpr int U = 8;
  int wid = (blockIdx.x * 256 + threadIdx.x) >> 6;
  int lane = threadIdx.x & 63;
  if (wid >= n) return;
  const int h = (lane * PER) / C;
  const int beg = rowptr[wid];
  const int end = rowptr[wid + 1];
  const float adh = a_dst[(size_t)wid * H + h];

  float m = -1e30f, den = 0.f;
  float acc[PER] = {};
  const ushort* xb = xl + lane * PER;

  for (int j = beg; j < end; j += U) {
    int s[U];
    #pragma unroll
    for (int u = 0; u < U; ++u) {
      int jj = j + u;
      s[u] = (jj < end) ? csr_src[jj] : wid;   // own row = always-valid dummy
    }
    // issue all row gathers
    ushort4 xv4[U];
    uint    xv2[U];
    #pragma unroll
    for (int u = 0; u < U; ++u) {
      if constexpr (PER == 4) xv4[u] = *(const ushort4*)(xb + (size_t)s[u] * F);
      else                    xv2[u] = *(const uint*)(xb + (size_t)s[u] * F);
    }
    // scores (identical within a head's lane group)
    float v[U];
    #pragma unroll
    for (int u = 0; u < U; ++u) {
      float t = a_src[(size_t)s[u] * H + h] + adh;
      t = (t > 0.f) ? t : NEG_SLOPE * t;
      v[u] = (j + u < end) ? t : -1e30f;       // exp(v-mn) underflows to 0
    }
    float gm = v[0];
    #pragma unroll
    for (int u = 1; u < U; ++u) gm = fmaxf(gm, v[u]);
    float mn = fmaxf(m, gm);
    float scale = __expf(m - mn);              // 0 on first group (m=-1e30)
    m = mn;
    float p[U], psum = 0.f;
    #pragma unroll
    for (int u = 0; u < U; ++u) { p[u] = __expf(v[u] - mn); psum += p[u]; }
    den = den * scale + psum;
    #pragma unroll
    for (int i = 0; i < PER; ++i) acc[i] *= scale;
    #pragma unroll
    for (int u = 0; u < U; ++u) {
      if constexpr (PER == 4) {
        acc[0] = fmaf(p[u], b2f(xv4[u].x), acc[0]);
        acc[1] = fmaf(p[u], b2f(xv4[u].y), acc[1]);
        acc[2] = fmaf(p[u], b2f(xv4[u].z), acc[2]);
        acc[3] = fmaf(p[u], b2f(xv4[u].w), acc[3]);
      } else {
        acc[0] = fmaf(p[u], b2f((ushort)(xv2[u] & 0xFFFF)), acc[0]);
        acc[1] = fmaf(p[u], b2f((ushort)(xv2[u] >> 16)), acc[1]);
      }
    }
  }

  float inv = 1.f / (den + 1e-16f);
  if constexpr (OUT_BF16) {
    ushort* od = (ushort*)out + (size_t)wid * F + lane * PER;
    float o[PER];
    #pragma unroll
    for (int i = 0; i < PER; ++i) o[i] = acc[i] * inv;
    if constexpr (RELU) {
      #pragma unroll
      for (int i = 0; i < PER; ++i) o[i] = fmaxf(o[i] + bias[lane * PER + i], 0.f);
    }
    if constexpr (PER == 4) {
      ushort4 ov = {f2b(o[0]), f2b(o[1]), f2b(o[2]), f2b(o[3])};
      *(ushort4*)od = ov;
    } else {
      uint ov = (uint)f2b(o[0]) | ((uint)f2b(o[1]) << 16);
      *(uint*)od = ov;
    }
  } else {
    float* od = (float*)out + (size_t)wid * F + lane * PER;
    if constexpr (PER == 4) {
      float4 ov = {acc[0] * inv, acc[1] * inv, acc[2] * inv, acc[3] * inv};
      *(float4*)od = ov;
    } else {
      float2 ov = {acc[0] * inv, acc[1] * inv};
      *(float2*)od = ov;
    }
  }
}

// ---------------- global mean pool (batch sorted) ----------------------------
__global__ __launch_bounds__(256) void pool_k(const float* __restrict__ h,
                                              const int* __restrict__ batch,
                                              float* __restrict__ pool, int n) {
  int ch = threadIdx.x & 127;
  int half = threadIdx.x >> 7;
  int n0 = blockIdx.x * 256;
  float run = 0.f;
  int curg = -1;
  for (int r = half; r < 256; r += 2) {
    int node = n0 + r;
    if (node >= n) break;
    int g = batch[node];
    if (g != curg) {
      if (curg >= 0) unsafeAtomicAdd(pool + curg * 128 + ch, run);
      run = 0.f;
      curg = g;
    }
    run += h[(size_t)node * 128 + ch];
  }
  if (curg >= 0) unsafeAtomicAdd(pool + curg * 128 + ch, run);
}

__global__ __launch_bounds__(256) void finalize_k(const float* __restrict__ pool,
                                                  const int* __restrict__ batch,
                                                  const float* __restrict__ bias2,
                                                  float* __restrict__ out, int n) {
  int t = blockIdx.x * 256 + threadIdx.x;
  if (t >= 8 * 128) return;
  int g = t >> 7, c = t & 127;
  int a = 0, b = n;
  while (a < b) { int mid = (a + b) >> 1; if (batch[mid] < g) a = mid + 1; else b = mid; }
  int lo = a;
  b = n;
  while (a < b) { int mid = (a + b) >> 1; if (batch[mid] < g + 1) a = mid + 1; else b = mid; }
  int hi = a;
  float cnt = (float)(hi - lo);
  out[t] = pool[t] / fmaxf(cnt, 1.f) + bias2[c];
}

extern "C" void kernel_launch(void* const* d_in, const int* in_sizes, int n_in,
                              void* d_out, int out_size, void* d_ws, size_t ws_size,
                              hipStream_t stream) {
  const float* x        = (const float*)d_in[0];
  const int*   ei       = (const int*)d_in[1];
  const int*   batch    = (const int*)d_in[2];
  const float* W1       = (const float*)d_in[3];
  const float* att_src1 = (const float*)d_in[4];
  const float* att_dst1 = (const float*)d_in[5];
  const float* bias1    = (const float*)d_in[6];
  const float* W2       = (const float*)d_in[7];
  const float* att_src2 = (const float*)d_in[8];
  const float* att_dst2 = (const float*)d_in[9];
  const float* bias2    = (const float*)d_in[10];
  float* out = (float*)d_out;

  const int E  = in_sizes[1] / 2;
  const int NN = in_sizes[2];
  const int ET = E + NN;
  const int* esrc = ei;
  const int* edst = ei + E;

  // ---- workspace layout ----
  char* w = (char*)d_ws;
  size_t woff = 0;
  auto walloc = [&](size_t bytes) -> char* {
    char* r = w + woff;
    woff += (bytes + 255) & ~(size_t)255;
    return r;
  };
  ushort* xl1    = (ushort*)walloc((size_t)NN * 256 * 2);  // xl1 bf16; later out2 f32 (NN*128)
  ushort* h1     = (ushort*)walloc((size_t)NN * 256 * 2);
  ushort* xl2    = (ushort*)walloc((size_t)NN * 128 * 2);
  float*  a_src1 = (float*)walloc((size_t)NN * 4 * 4);
  float*  a_dst1 = (float*)walloc((size_t)NN * 4 * 4);
  float*  a_src2 = (float*)walloc((size_t)NN * 4);
  float*  a_dst2 = (float*)walloc((size_t)NN * 4);
  int*    rowptr = (int*)walloc((size_t)(NN + 1) * 4);
  int*    cursor = (int*)walloc((size_t)NN * 4);
  int*    hist   = (int*)walloc((size_t)NN * 4);
  int*    csrsrc = (int*)walloc((size_t)ET * 4);
  ushort* Bp1    = (ushort*)walloc(128 * 256 * 2);
  ushort* Bp2    = (ushort*)walloc(256 * 128 * 2);
  int*    chunks = (int*)walloc(256 * 4);
  int*    chunko = (int*)walloc(256 * 4);
  float*  pool   = (float*)walloc(8 * 128 * 4);
  float*  out2   = (float*)xl1;   // xl1 dead after agg1 (gemm2 reads h1)

  dim3 blk(256);
  const int nbE = (ET + 255) / 256;
  const int nbN4 = (NN + 3) / 4;
  const int nchunks = (NN + 1023) / 1024;
  const int gblocks = (NN / 16 + 3) / 4;   // NN divisible by 16 (50000)

  // ---- CSR build ----
  hipMemsetAsync(hist, 0, (size_t)NN * 4, stream);
  hipMemsetAsync(pool, 0, 8 * 128 * 4, stream);
  hist_k<<<nbE, blk, 0, stream>>>(edst, hist, E, NN);
  scan1_k<<<nchunks, blk, 0, stream>>>(hist, rowptr, chunks, NN);
  scan2_k<<<1, 64, 0, stream>>>(chunks, chunko, nchunks);
  addoff_k<<<(NN + 255) / 256, blk, 0, stream>>>(rowptr, cursor, chunko, NN, ET);
  scatter_k<<<nbE, blk, 0, stream>>>(esrc, edst, cursor, csrsrc, E, NN);

  // ---- weight packing ----
  pack_w<<<(128 * 256 + 255) / 256, blk, 0, stream>>>(W1, Bp1, 128, 256);
  pack_w<<<(256 * 128 + 255) / 256, blk, 0, stream>>>(W2, Bp2, 256, 128);

  // ---- layer 1: fused GEMM (f32 A) + attn coefs, then flash agg ----
  gemm_attn<256, 128, 64, 4, true><<<gblocks, blk, 0, stream>>>(
      x, Bp1, att_src1, att_dst1, xl1, a_src1, a_dst1, NN);
  agg_flash<4, 64, true, true><<<nbN4, blk, 0, stream>>>(rowptr, csrsrc, a_src1, a_dst1,
                                                         xl1, bias1, h1, NN);

  // ---- layer 2 ----
  gemm_attn<128, 256, 128, 1, false><<<gblocks, blk, 0, stream>>>(
      h1, Bp2, att_src2, att_dst2, xl2, a_src2, a_dst2, NN);
  agg_flash<1, 128, false, false><<<nbN4, blk, 0, stream>>>(rowptr, csrsrc, a_src2, a_dst2,
                                                            xl2, nullptr, out2, NN);

  // ---- pool + finalize ----
  pool_k<<<(NN + 255) / 256, blk, 0, stream>>>(out2, batch, pool, NN);
  finalize_k<<<4, blk, 0, stream>>>(pool, batch, bias2, out, NN);
}